// Round 10
// baseline (1281.538 us; speedup 1.0000x reference)
//
#include <hip/hip_runtime.h>
#include <hip/hip_fp16.h>

namespace {

constexpr int B = 4;
constexpr int N = 2048;
constexpr int E = 1024;
constexpr int H = 16;
constexpr int D = 64;
constexpr int M = B * N;  // 8192

typedef __attribute__((ext_vector_type(8))) short bf16x8;
typedef __attribute__((ext_vector_type(8))) _Float16 f16x8;
typedef __attribute__((ext_vector_type(4))) _Float16 f16x4;
typedef __attribute__((ext_vector_type(4))) float f32x4;

__device__ inline ushort bf16_rne(float f) {
  unsigned u = __float_as_uint(f);
  return (ushort)((u + 0x7FFFu + ((u >> 16) & 1u)) >> 16);
}
// fp32 -> hi (truncated bf16) + lo (rne bf16 of remainder); hi+lo ~ 17-bit mantissa
__device__ inline void split2(float f, ushort& hi, ushort& lo) {
  unsigned u = __float_as_uint(f);
  hi = (ushort)(u >> 16);
  lo = bf16_rne(f - __uint_as_float(u & 0xFFFF0000u));
}

// ---------------------------------------------------------------------------
// Elementwise fp32 -> (hi, lo) bf16 split
// ---------------------------------------------------------------------------
__global__ __launch_bounds__(256) void split_kernel(
    const float* __restrict__ in, ushort* __restrict__ hi,
    ushort* __restrict__ lo, int n4) {
  int i = blockIdx.x * blockDim.x + threadIdx.x;
  const int stride = gridDim.x * blockDim.x;
  for (; i < n4; i += stride) {
    const float4 f = ((const float4*)in)[i];
    ushort4 h, l;
    split2(f.x, h.x, l.x);
    split2(f.y, h.y, l.y);
    split2(f.z, h.z, l.z);
    split2(f.w, h.w, l.w);
    ((ushort4*)hi)[i] = h;
    ((ushort4*)lo)[i] = l;
  }
}

// ---------------------------------------------------------------------------
// bf16x3 MFMA GEMM. Tile 128x128, BK=32, 4 waves.
// MODE 0 epilogue: col = h*192 + d*3 + s ->
//   s==0: Q *(1/8) split -> Qh/Ql  [B,H,N,D] bf16
//   s==1: K split        -> Kh/Kl  [B,H,N,D] bf16
//   s==2: V -> Vtb [B,H,kt=N/64][d=64][64] fp16 tile-blocked transpose
// MODE 1 epilogue: out[m][col] = acc + bias (fp32)
// ---------------------------------------------------------------------------
template <int MODE>
__global__ __launch_bounds__(256) void gemm_x3(
    const ushort* __restrict__ Ahg, const ushort* __restrict__ Alg,
    const ushort* __restrict__ Bhg, const ushort* __restrict__ Blg,
    const float* __restrict__ bias, ushort* __restrict__ qh,
    ushort* __restrict__ ql, ushort* __restrict__ kh, ushort* __restrict__ kl,
    ushort* __restrict__ vt, float* __restrict__ outp) {
  __shared__ ushort LAh[4096], LAl[4096], LBh[4096], LBl[4096];
  const int tid = threadIdx.x;
  const int l = tid & 63, wid = tid >> 6;
  const int wr = wid >> 1, wc = wid & 1;
  const int lr = l & 15, kg = l >> 4;
  const int m0 = blockIdx.x * 128, n0 = blockIdx.y * 128;

  f32x4 acc[4][4];
#pragma unroll
  for (int i = 0; i < 4; ++i)
#pragma unroll
    for (int j = 0; j < 4; ++j) acc[i][j] = (f32x4){0.f, 0.f, 0.f, 0.f};

  for (int k0 = 0; k0 < E; k0 += 32) {
    const ushort* gAh = Ahg + (size_t)m0 * E + k0;
    const ushort* gAl = Alg + (size_t)m0 * E + k0;
    const ushort* gBh = Bhg + (size_t)n0 * E + k0;
    const ushort* gBl = Blg + (size_t)n0 * E + k0;
    __syncthreads();
    auto stage = [&](const ushort* gp, ushort* lp, int half) {
      const int c = half * 256 + tid;
      __builtin_amdgcn_global_load_lds(
          (__attribute__((address_space(1))) void*)(gp + (size_t)(c >> 2) * E +
                                                    (c & 3) * 8),
          (__attribute__((address_space(3))) void*)(lp +
                                                    (half * 256 + (tid & ~63)) * 8),
          16, 0, 0);
    };
    stage(gAh, LAh, 0); stage(gAh, LAh, 1);
    stage(gAl, LAl, 0); stage(gAl, LAl, 1);
    stage(gBh, LBh, 0); stage(gBh, LBh, 1);
    stage(gBl, LBl, 0); stage(gBl, LBl, 1);
    __syncthreads();

    bf16x8 aH[4], aL[4], bH[4], bL[4];
#pragma unroll
    for (int rb = 0; rb < 4; ++rb) {
      const int off = (wr * 64 + rb * 16 + lr) * 32 + kg * 8;
      aH[rb] = *(const bf16x8*)(LAh + off);
      aL[rb] = *(const bf16x8*)(LAl + off);
    }
#pragma unroll
    for (int cb = 0; cb < 4; ++cb) {
      const int off = (wc * 64 + cb * 16 + lr) * 32 + kg * 8;
      bH[cb] = *(const bf16x8*)(LBh + off);
      bL[cb] = *(const bf16x8*)(LBl + off);
    }
#pragma unroll
    for (int rb = 0; rb < 4; ++rb)
#pragma unroll
      for (int cb = 0; cb < 4; ++cb) {
        acc[rb][cb] = __builtin_amdgcn_mfma_f32_16x16x32_bf16(
            aH[rb], bH[cb], acc[rb][cb], 0, 0, 0);
        acc[rb][cb] = __builtin_amdgcn_mfma_f32_16x16x32_bf16(
            aH[rb], bL[cb], acc[rb][cb], 0, 0, 0);
        acc[rb][cb] = __builtin_amdgcn_mfma_f32_16x16x32_bf16(
            aL[rb], bH[cb], acc[rb][cb], 0, 0, 0);
      }
  }

  // C/D layout: col = lane&15, row = (lane>>4)*4 + reg.
#pragma unroll
  for (int cb = 0; cb < 4; ++cb) {
    const int col = n0 + wc * 64 + cb * 16 + lr;
    const float bv = bias[col];
    if (MODE == 0) {
      const int h = col / 192;
      const int rem = col - h * 192;
      const int dd = rem / 3;
      const int s = rem - dd * 3;
      if (s == 2) {
        // V: 4 consecutive n -> one 8B store into the [64][64] kt tile
#pragma unroll
        for (int rb = 0; rb < 4; ++rb) {
          const int m = m0 + wr * 64 + rb * 16 + kg * 4;
          const int bb = m >> 11, nn = m & (N - 1);
          f16x4 pk;
#pragma unroll
          for (int r = 0; r < 4; ++r)
            pk[r] = (_Float16)(acc[rb][cb][r] + bv);
          const size_t vidx =
              ((((size_t)bb * H + h) * (N / 64) + (nn >> 6)) * 64 + dd) * 64 +
              (nn & 63);
          *(f16x4*)((_Float16*)vt + vidx) = pk;
        }
      } else {
#pragma unroll
        for (int rb = 0; rb < 4; ++rb)
#pragma unroll
          for (int r = 0; r < 4; ++r) {
            const int m = m0 + wr * 64 + rb * 16 + kg * 4 + r;
            const int bb = m >> 11, nn = m & (N - 1);
            float v = acc[rb][cb][r] + bv;
            ushort hi, lo;
            const size_t idx = (((size_t)bb * H + h) * N + nn) * D + dd;
            if (s == 0) {
              v *= 0.125f;  // fold 1/sqrt(D), exact pow2
              split2(v, hi, lo);
              qh[idx] = hi; ql[idx] = lo;
            } else {
              split2(v, hi, lo);
              kh[idx] = hi; kl[idx] = lo;
            }
          }
      }
    } else {
#pragma unroll
      for (int rb = 0; rb < 4; ++rb)
#pragma unroll
        for (int r = 0; r < 4; ++r) {
          const int m = m0 + wr * 64 + rb * 16 + kg * 4 + r;
          outp[(size_t)m * E + col] = acc[rb][cb][r] + bv;
        }
    }
  }
}

// ---------------------------------------------------------------------------
// MFMA flash attention v6: spill-free register-staged pipeline (v5) with the
// two-half softmax made EXACT: each 32-column half is an online-softmax block
// -- QK^T(half) -> softmax update (current m) -> write P(half) -> PV(half,
// K=32) immediately. A later max increase rescales o, which already includes
// this half's PV, so no stale-P in LDS (v5's bug).
// Per iter: vmcnt(0) -> ds_write S -> issue loads kt+1 -> lgkmcnt(0) ->
// s_barrier -> compute; prefetch loads fly across barrier + compute.
// QK^T: bf16x3; PV: fp16; P in per-wave swizzled LDS buffer.
// ---------------------------------------------------------------------------
__global__ __launch_bounds__(256, 2) void attn_mfma(
    const ushort* __restrict__ Qh, const ushort* __restrict__ Ql,
    const ushort* __restrict__ Kh, const ushort* __restrict__ Kl,
    const ushort* __restrict__ Vt, ushort* __restrict__ Aoh,
    ushort* __restrict__ Aol) {
  __shared__ ushort KhL[2][4096], KlL[2][4096], VtL[2][4096], PsL[4][4096];
  const int tid = threadIdx.x;
  const int l = tid & 63, w = tid >> 6;
  const int lr = l & 15, g = l >> 4;
  const int bh = blockIdx.x, bb = bh >> 4, hh = bh & 15;
  const int q0 = blockIdx.y * 256 + w * 64;

  // Staging: thread covers row sr, 16B chunks sc and sc+4 of the 128B row.
  // Global reads linear/coalesced; LDS slot XOR-swizzled.
  const int sr = tid >> 2;
  const int sc = tid & 3;
  const int slotA = sr * 8 + (sc ^ (sr & 7));
  const int slotB = sr * 8 + ((sc + 4) ^ (sr & 7));

  // Q A-fragments (scale pre-folded): row = lane&15, k = (lane>>4)*8 + e
  bf16x8 qfh[4][2], qfl[4][2];
#pragma unroll
  for (int rb = 0; rb < 4; ++rb)
#pragma unroll
    for (int ks = 0; ks < 2; ++ks) {
      const size_t off =
          ((size_t)bh * N + q0 + rb * 16 + lr) * D + ks * 32 + g * 8;
      qfh[rb][ks] = *(const bf16x8*)(Qh + off);
      qfl[rb][ks] = *(const bf16x8*)(Ql + off);
    }

  f32x4 o[4][4];
  float m_[4][4], l_[4][4];
#pragma unroll
  for (int rb = 0; rb < 4; ++rb)
#pragma unroll
    for (int r = 0; r < 4; ++r) {
      m_[rb][r] = -1e30f;
      l_[rb][r] = 0.f;
      o[rb][r] = (f32x4){0.f, 0.f, 0.f, 0.f};
    }

  ushort* Pw = &PsL[w][0];
  constexpr int NT = N / 64;

#define LOAD_SET(KT)                                                          \
  do {                                                                        \
    const size_t ko = ((size_t)bh * N + (size_t)(KT) * 64 + sr) * 64;         \
    const size_t vo = (((size_t)bh * (N / 64) + (KT)) * 64 + sr) * 64;        \
    S[0] = *(const uint4*)(Kh + ko + sc * 8);                                 \
    S[1] = *(const uint4*)(Kh + ko + (sc + 4) * 8);                           \
    S[2] = *(const uint4*)(Kl + ko + sc * 8);                                 \
    S[3] = *(const uint4*)(Kl + ko + (sc + 4) * 8);                           \
    S[4] = *(const uint4*)(Vt + vo + sc * 8);                                 \
    S[5] = *(const uint4*)(Vt + vo + (sc + 4) * 8);                           \
  } while (0)

#define WRITE_SET(BUF)                                                        \
  do {                                                                        \
    *(uint4*)(&KhL[BUF][slotA * 8]) = S[0];                                   \
    *(uint4*)(&KhL[BUF][slotB * 8]) = S[1];                                   \
    *(uint4*)(&KlL[BUF][slotA * 8]) = S[2];                                   \
    *(uint4*)(&KlL[BUF][slotB * 8]) = S[3];                                   \
    *(uint4*)(&VtL[BUF][slotA * 8]) = S[4];                                   \
    *(uint4*)(&VtL[BUF][slotB * 8]) = S[5];                                   \
  } while (0)

  uint4 S[6];
  LOAD_SET(0);

  for (int kt = 0; kt < NT; ++kt) {
    const int buf = kt & 1;
    asm volatile("s_waitcnt vmcnt(0)" ::: "memory");  // tile kt in S
    WRITE_SET(buf);
    if (kt + 1 < NT) LOAD_SET(kt + 1);  // fly across barrier + compute
    asm volatile("s_waitcnt lgkmcnt(0)" ::: "memory");
    __builtin_amdgcn_s_barrier();  // buf ready for all waves

    const ushort* KhC = &KhL[buf][0];
    const ushort* KlC = &KlL[buf][0];
    const ushort* VtC = &VtL[buf][0];

    // Two 32-column halves; each is a complete online-softmax block:
    // QK^T -> softmax (current m) -> P write -> PV (K=32). Exact.
#pragma unroll
    for (int half = 0; half < 2; ++half) {
      f32x4 s4[4][2];
#pragma unroll
      for (int rb = 0; rb < 4; ++rb)
#pragma unroll
        for (int c2 = 0; c2 < 2; ++c2) s4[rb][c2] = (f32x4){0.f, 0.f, 0.f, 0.f};
      __builtin_amdgcn_s_setprio(1);
#pragma unroll
      for (int ks = 0; ks < 2; ++ks) {
        bf16x8 kfh[2], kfl[2];
#pragma unroll
        for (int c2 = 0; c2 < 2; ++c2) {
          const int cb = half * 2 + c2;
          const int sl = (cb * 16 + lr) * 8 + ((ks * 4 + g) ^ (lr & 7));
          kfh[c2] = *(const bf16x8*)(KhC + sl * 8);
          kfl[c2] = *(const bf16x8*)(KlC + sl * 8);
        }
#pragma unroll
        for (int rb = 0; rb < 4; ++rb)
#pragma unroll
          for (int c2 = 0; c2 < 2; ++c2) {
            s4[rb][c2] = __builtin_amdgcn_mfma_f32_16x16x32_bf16(
                qfh[rb][ks], kfh[c2], s4[rb][c2], 0, 0, 0);
            s4[rb][c2] = __builtin_amdgcn_mfma_f32_16x16x32_bf16(
                qfh[rb][ks], kfl[c2], s4[rb][c2], 0, 0, 0);
            s4[rb][c2] = __builtin_amdgcn_mfma_f32_16x16x32_bf16(
                qfl[rb][ks], kfh[c2], s4[rb][c2], 0, 0, 0);
          }
      }
      __builtin_amdgcn_s_setprio(0);

      // Online softmax update over this half's 32 columns.
#pragma unroll
      for (int rb = 0; rb < 4; ++rb)
#pragma unroll
        for (int r = 0; r < 4; ++r) {
          float mx = fmaxf(s4[rb][0][r], s4[rb][1][r]);
          mx = fmaxf(mx, __shfl_xor(mx, 1, 16));
          mx = fmaxf(mx, __shfl_xor(mx, 2, 16));
          mx = fmaxf(mx, __shfl_xor(mx, 4, 16));
          mx = fmaxf(mx, __shfl_xor(mx, 8, 16));
          const float mn = fmaxf(m_[rb][r], mx);
          const float fac = __expf(m_[rb][r] - mn);
          m_[rb][r] = mn;
          float sum = 0.f;
#pragma unroll
          for (int c2 = 0; c2 < 2; ++c2) {
            const float p = __expf(s4[rb][c2][r] - mn);
            s4[rb][c2][r] = p;
            sum += p;
          }
          sum += __shfl_xor(sum, 1, 16);
          sum += __shfl_xor(sum, 2, 16);
          sum += __shfl_xor(sum, 4, 16);
          sum += __shfl_xor(sum, 8, 16);
          l_[rb][r] = l_[rb][r] * fac + sum;
#pragma unroll
          for (int cb = 0; cb < 4; ++cb) o[rb][cb][r] *= fac;
          const int row = rb * 16 + g * 4 + r;
#pragma unroll
          for (int c2 = 0; c2 < 2; ++c2) {
            const int cb = half * 2 + c2;
            const int idx = (row * 64 + cb * 16 + lr) ^ ((row & 7) << 3);
            ((_Float16*)Pw)[idx] = (_Float16)s4[rb][c2][r];
          }
        }

      // PV for this half (K=32): o += P[:, half*32..+32] @ V[half*32..+32, :]
      __builtin_amdgcn_s_setprio(1);
      {
        f16x8 pf[4], vf[4];
#pragma unroll
        for (int rb = 0; rb < 4; ++rb) {
          const int sl = (rb * 16 + lr) * 8 + ((half * 4 + g) ^ (lr & 7));
          pf[rb] = *(const f16x8*)(Pw + sl * 8);
        }
#pragma unroll
        for (int cb = 0; cb < 4; ++cb) {
          const int sl = (cb * 16 + lr) * 8 + ((half * 4 + g) ^ (lr & 7));
          vf[cb] = *(const f16x8*)(VtC + sl * 8);
        }
#pragma unroll
        for (int rb = 0; rb < 4; ++rb)
#pragma unroll
          for (int cb = 0; cb < 4; ++cb)
            o[rb][cb] = __builtin_amdgcn_mfma_f32_16x16x32_f16(
                pf[rb], vf[cb], o[rb][cb], 0, 0, 0);
      }
      __builtin_amdgcn_s_setprio(0);
    }
  }
#undef LOAD_SET
#undef WRITE_SET

  // Epilogue: normalize, split hi/lo, write [b, n, h*D + d]
#pragma unroll
  for (int rb = 0; rb < 4; ++rb)
#pragma unroll
    for (int r = 0; r < 4; ++r) {
      const float inv = 1.f / l_[rb][r];
      const int n = q0 + rb * 16 + g * 4 + r;
      const size_t base = ((size_t)bb * N + n) * E + hh * D;
#pragma unroll
      for (int cb = 0; cb < 4; ++cb) {
        ushort hi, lo;
        split2(o[rb][cb][r] * inv, hi, lo);
        Aoh[base + cb * 16 + lr] = hi;
        Aol[base + cb * 16 + lr] = lo;
      }
    }
}

}  // namespace

extern "C" void kernel_launch(void* const* d_in, const int* in_sizes, int n_in,
                              void* d_out, int out_size, void* d_ws,
                              size_t ws_size, hipStream_t stream) {
  (void)in_sizes; (void)n_in; (void)out_size; (void)ws_size;
  const float* x      = (const float*)d_in[0];
  const float* w_qkv  = (const float*)d_in[1];
  const float* b_qkv  = (const float*)d_in[2];
  const float* w_proj = (const float*)d_in[3];
  const float* b_proj = (const float*)d_in[4];
  float* out = (float*)d_out;

  constexpr size_t MB = 1ull << 20;
  char* w = (char*)d_ws;
  ushort* xh  = (ushort*)(w + 0 * MB);    // 16 MB
  ushort* xl  = (ushort*)(w + 16 * MB);   // 16 MB
  ushort* wqh = (ushort*)(w + 32 * MB);   // 6 MB
  ushort* wql = (ushort*)(w + 38 * MB);   // 6 MB
  ushort* wph = (ushort*)(w + 44 * MB);   // 2 MB
  ushort* wpl = (ushort*)(w + 46 * MB);   // 2 MB
  ushort* Aoh = (ushort*)(w + 48 * MB);   // 16 MB
  ushort* Aol = (ushort*)(w + 64 * MB);   // 16 MB
  ushort* Qh  = (ushort*)(w + 80 * MB);   // 16 MB
  ushort* Ql  = (ushort*)(w + 96 * MB);   // 16 MB
  ushort* Kh  = (ushort*)(w + 112 * MB);  // 16 MB
  ushort* Kl  = (ushort*)(w + 128 * MB);  // 16 MB
  ushort* Vt  = (ushort*)(w + 144 * MB);  // 16 MB (fp16, tile-blocked)

  split_kernel<<<2048, 256, 0, stream>>>(x, xh, xl, (M * E) / 4);
  split_kernel<<<1024, 256, 0, stream>>>(w_qkv, wqh, wql, (3 * E * E) / 4);
  split_kernel<<<512, 256, 0, stream>>>(w_proj, wph, wpl, (E * E) / 4);

  gemm_x3<0><<<dim3(M / 128, 3 * E / 128), 256, 0, stream>>>(
      xh, xl, wqh, wql, b_qkv, Qh, Ql, Kh, Kl, Vt, nullptr);

  attn_mfma<<<dim3(B * H, N / 256), 256, 0, stream>>>(Qh, Ql, Kh, Kl, Vt, Aoh,
                                                      Aol);

  gemm_x3<1><<<dim3(M / 128, E / 128), 256, 0, stream>>>(
      Aoh, Aol, wph, wpl, b_proj, nullptr, nullptr, nullptr, nullptr, nullptr,
      out);
}